// Round 13
// baseline (213.449 us; speedup 1.0000x reference)
//
#include <hip/hip_runtime.h>

#define NNODES 8192
#define NEDGES 65536

#define K_PACK   0.02209708691f   // 1/sqrt(2048)
#define K_P1SV   0.01804219593f   // 1/(32*sqrt3)
#define K_VVS    0.04419417382f   // 1/sqrt(512)
#define K_VS     0.03608439182f   // 1/(16*sqrt3)
#define K_VVV    0.02551551815f   // K_VS/sqrt2
#define K_DOT    0.57735026919f
#define K_PRELN  0.35355339059f
#define C_EMB    8.4335730689f

typedef unsigned int uint32;
typedef unsigned short ushort16;
typedef __attribute__((ext_vector_type(8))) short short8;
typedef __attribute__((ext_vector_type(4))) float floatx4;

__device__ __forceinline__ float siluf(float x) { return x / (1.0f + __expf(-x)); }
__device__ __forceinline__ float susf(float t) { return t > 0.0f ? __expf(-1.0f / t) : 0.0f; }
__device__ __forceinline__ ushort16 f2bf(float f) {
  uint32 u = __float_as_uint(f);
  return (ushort16)((u + 0x7fffu + ((u >> 16) & 1u)) >> 16);
}
__device__ __forceinline__ float bflo(uint32 v) { return __uint_as_float(v << 16); }
__device__ __forceinline__ float bfhi(uint32 v) { return __uint_as_float(v & 0xffff0000u); }
__device__ __forceinline__ float bfs(ushort16 v) { return __uint_as_float((uint32)v << 16); }

// ---------- prep: edge geom + 3 MLPs (split across 3x blocks, W in LDS), CSR, packs ----------
__global__ __launch_bounds__(256) void k_prep(
    const float* __restrict__ pos, const int* __restrict__ z, const int* __restrict__ mol,
    const int* __restrict__ esrc, const int* __restrict__ edst,
    const float* __restrict__ Ez, const float* __restrict__ Em,
    const float* __restrict__ W10, const float* __restrict__ W11, const float* __restrict__ W12,
    const float* __restrict__ W20, const float* __restrict__ W21, const float* __restrict__ W22,
    int* __restrict__ combo, ushort16* __restrict__ X0cb, float* __restrict__ sh,
    ushort16* __restrict__ h0b, ushort16* __restrict__ h1b, ushort16* __restrict__ h2b,
    ushort16* __restrict__ Bp0, ushort16* __restrict__ Bp1, ushort16* __restrict__ Bp2,
    ushort16* __restrict__ Bpw1, ushort16* __restrict__ Bpw2,
    int* __restrict__ deg, int* __restrict__ eidx) {
  __shared__ float Wl[320];
  int b = blockIdx.x;
  if (b < 768) {
    // ---- edge MLP phase: which = 0,1,2 ; 256 blocks each ----
    int which = b >> 8;
    int e = ((b & 255) << 8) + threadIdx.x;
    const float* W = (which == 0) ? W10 : (which == 1) ? W11 : W12;
    for (int i = threadIdx.x; i < 320; i += 256) Wl[i] = W[i];
    __syncthreads();
    int s = esrc[e], d = edst[e];
    float vx = pos[d * 3 + 0] - pos[s * 3 + 0];
    float vy = pos[d * 3 + 1] - pos[s * 3 + 1];
    float vz = pos[d * 3 + 2] - pos[s * 3 + 2];
    float len = sqrtf(vx * vx + vy * vy + vz * vz);
    if (which == 0) {
      int p = atomicAdd(&deg[d], 1);
      if (p < 64) eidx[(size_t)d * 64 + p] = e;
      float inv = 1.7320508076f / fmaxf(len, 1e-9f);
      sh[e * 3 + 0] = vx * inv; sh[e * 3 + 1] = vy * inv; sh[e * 3 + 2] = vz * inv;
    }
    float emb[10];
#pragma unroll
    for (int k = 0; k < 10; ++k) {
      float u = len * 1.1f - (float)(k + 1);
      emb[k] = C_EMB * susf(u + 1.0f) * susf(1.0f - u);
    }
    float H[32];
#pragma unroll
    for (int m = 0; m < 32; ++m) {
      float t = 0.f;
#pragma unroll
      for (int k = 0; k < 10; ++k) t += emb[k] * Wl[k * 32 + m];
      H[m] = siluf(t);
    }
    ushort16* hb = (which == 0) ? h0b : (which == 1) ? h1b : h2b;
    uint32* hp = (uint32*)(hb + (size_t)e * 32);
#pragma unroll
    for (int m = 0; m < 16; ++m)
      hp[m] = (uint32)f2bf(H[2 * m]) | ((uint32)f2bf(H[2 * m + 1]) << 16);
    return;
  }
  int idx = (b - 768) * 256 + threadIdx.x;
  if (idx < NNODES) { combo[idx] = z[idx] * 2 + mol[idx]; return; }
  idx -= NNODES;
  if (idx < 16384) {  // X0cb[256][64] bf16
    int c = idx >> 6, j = idx & 63;
    float v = 0.f;
    if (c < 200) {
      int zz = c >> 1, mm = c & 1;
      v = (j < 48) ? Ez[zz * 48 + j] : Em[mm * 16 + (j - 48)];
    }
    X0cb[idx] = f2bf(v);
    return;
  }
  idx -= 16384;
  if (idx < 81920) {  // Bp0[tile(80)][kh(2)][lane(64)][j(8)] bf16, K=64
    int tile = idx >> 10; int r = idx & 1023;
    int kh = r >> 9; int rr = r & 511;
    int lane = rr >> 3, j = rr & 7;
    int k = kh * 32 + (lane >> 4) * 8 + j;
    int n = tile * 16 + (lane & 15);
    int c = n >> 5, m = n & 31;
    int col = (c < 32) ? (k * 32 + c) : (2048 + k * 8 + (c - 32));
    Bp0[idx] = f2bf(W20[m * 2560 + col] * K_PACK);
    return;
  }
  idx -= 81920;
  if (idx < 40960) {  // Bp1[tile(80)][lane][j] bf16, K=32
    int tile = idx >> 9; int rr = idx & 511;
    int lane = rr >> 3, j = rr & 7;
    int k = (lane >> 4) * 8 + j;
    int n = tile * 16 + (lane & 15);
    int c = n >> 5, m = n & 31;
    float v = (c < 32) ? W21[m * 1664 + k * 32 + c] * K_PACK
                       : W21[m * 1664 + 1280 + k * 8 + (c - 32)] * K_P1SV;
    Bp1[idx] = f2bf(v);
    return;
  }
  idx -= 40960;
  if (idx < 16384) {  // Bp2[tile(32)][lane][j] bf16, K=32
    int tile = idx >> 9; int rr = idx & 511;
    int lane = rr >> 3, j = rr & 7;
    int k = (lane >> 4) * 8 + j;
    int n = tile * 16 + (lane & 15);
    int c = n >> 5, m = n & 31;
    Bp2[idx] = f2bf(W22[m * 640 + k * 16 + c] * K_PACK);
    return;
  }
  idx -= 16384;
  if (idx < 12288) {  // Bpw1: col n = c*8+u (vvs) | 256+vo*8+u (vs) | 320+vo*8+u (vvv)
    int tile = idx >> 9; int rr = idx & 511;
    int lane = rr >> 3, j = rr & 7;
    int m = (lane >> 4) * 8 + j;
    int n = tile * 16 + (lane & 15);
    float v;
    if (n < 256) {
      int c = n >> 3, u = n & 7;
      v = W21[m * 1664 + 1024 + u * 32 + c] * K_VVS;
    } else if (n < 320) {
      int vo = (n - 256) >> 3, u = n & 7;
      v = W21[m * 1664 + 1536 + u * 8 + vo] * K_VS;
    } else {
      int vo = (n - 320) >> 3, u = n & 7;
      v = W21[m * 1664 + 1600 + u * 8 + vo] * K_VVV;
    }
    Bpw1[idx] = f2bf(v);
    return;
  }
  idx -= 12288;
  {  // Bpw2 u-major: tile = u (8 tiles), col c = lane&15 -> W22 natural vvs layout
    int tile = idx >> 9; int rr = idx & 511;
    int lane = rr >> 3, j = rr & 7;
    int m = (lane >> 4) * 8 + j;
    int c = lane & 15;
    Bpw2[idx] = f2bf(W22[m * 640 + 512 + tile * 16 + c] * K_VVS);
  }
}

// ---------- MFMA GEMM tile body ----------
__device__ __forceinline__ void gemm_tile(
    const ushort16* __restrict__ A, const ushort16* __restrict__ Bp, ushort16* __restrict__ C,
    int N, int K, int bx, int by, int wave, int lane) {
  int m0 = bx * 64 + wave * 16;
  int n0 = by * 64;
  int row = lane & 15, q = lane >> 4;
  int nkh = K >> 5;
  floatx4 acc[4];
  floatx4 zero = {0.f, 0.f, 0.f, 0.f};
#pragma unroll
  for (int t = 0; t < 4; ++t) acc[t] = zero;
  for (int kh = 0; kh < nkh; ++kh) {
    short8 a = *reinterpret_cast<const short8*>(A + (size_t)(m0 + row) * K + kh * 32 + q * 8);
#pragma unroll
    for (int t = 0; t < 4; ++t) {
      int T = (n0 >> 4) + t;
      short8 b = *reinterpret_cast<const short8*>(Bp + ((size_t)T * nkh + kh) * 512 + lane * 8);
      acc[t] = __builtin_amdgcn_mfma_f32_16x16x32_bf16(a, b, acc[t], 0, 0, 0);
    }
  }
  int colb = n0 + row;
#pragma unroll
  for (int t = 0; t < 4; ++t)
#pragma unroll
    for (int r = 0; r < 4; ++r)
      C[(size_t)(m0 + q * 4 + r) * N + colb + t * 16] = f2bf(acc[t][r]);
}

__global__ __launch_bounds__(256) void k_gemm_mfma(
    const ushort16* __restrict__ A, const ushort16* __restrict__ Bp, ushort16* __restrict__ C,
    int N, int K) {
  gemm_tile(A, Bp, C, N, K, blockIdx.x, blockIdx.y, threadIdx.x >> 6, threadIdx.x & 63);
}

// ---------- fused block-0 gather: per dst node, inline MFMA P-dot over incoming edges + LN ----------
__global__ __launch_bounds__(256) void k_gather0(
    const int* __restrict__ deg, const int* __restrict__ eidx,
    const int* __restrict__ combo, const int* __restrict__ esrc,
    const float* __restrict__ sh, const ushort16* __restrict__ hb,
    const ushort16* __restrict__ Pb,
    const float* __restrict__ g, const float* __restrict__ b,
    ushort16* __restrict__ xsb, float* __restrict__ xvf) {
  int n = __builtin_amdgcn_readfirstlane(blockIdx.x * 4 + (threadIdx.x >> 6));
  int lane = threadIdx.x & 63;
  int row = lane & 15, q = lane >> 4;
  int cnt = deg[n]; if (cnt > 64) cnt = 64;
  const int* ep = eidx + (size_t)n * 64;
  int lv = lane - 32;
  int vq = (lv >= 0) ? ((lv / 3 > 7) ? 7 : lv / 3) : 0;
  int vi = (lv >= 0) ? (lv - (lv / 3) * 3) : 0;
  int c2 = 32 + row; if (c2 > 39) c2 = 39;
  floatx4 zero = {0.f, 0.f, 0.f, 0.f};
  float v = 0.f;
  for (int j = 0; j < cnt; ++j) {
    int e = __builtin_amdgcn_readfirstlane(ep[j]);
    int s = __builtin_amdgcn_readfirstlane(esrc[e]);
    int rp = __builtin_amdgcn_readfirstlane(combo[s]);
    float sh0 = sh[e * 3 + 0], sh1 = sh[e * 3 + 1], sh2 = sh[e * 3 + 2];
    short8 af = *reinterpret_cast<const short8*>(hb + (size_t)e * 32 + q * 8);
    const ushort16* Pr = Pb + (size_t)rp * 1280;
    short8 bf0 = *reinterpret_cast<const short8*>(Pr + row * 32 + q * 8);
    short8 bf1 = *reinterpret_cast<const short8*>(Pr + (16 + row) * 32 + q * 8);
    short8 bf2 = *reinterpret_cast<const short8*>(Pr + c2 * 32 + q * 8);
    floatx4 p0 = __builtin_amdgcn_mfma_f32_16x16x32_bf16(af, bf0, zero, 0, 0, 0);
    floatx4 p1 = __builtin_amdgcn_mfma_f32_16x16x32_bf16(af, bf1, zero, 0, 0, 0);
    floatx4 p2 = __builtin_amdgcn_mfma_f32_16x16x32_bf16(af, bf2, zero, 0, 0, 0);
    // broadcast-A MFMA: lane L holds channel (L&15) of each tile in reg 0
    float pv2 = __shfl(p2[0], vq, 64);
    float pdot = (lane < 16) ? p0[0] : (lane < 32) ? p1[0] : pv2;
    float mult = (lane < 32) ? 1.0f : ((vi == 0) ? sh0 : (vi == 1) ? sh1 : sh2);
    v += pdot * mult;
  }
  v *= K_PRELN;
  if (lane >= 56) v = 0.f;
  float sm = v, sq = v * v;
#pragma unroll
  for (int off = 32; off > 0; off >>= 1) {
    sm += __shfl_xor(sm, off, 64);
    sq += __shfl_xor(sq, off, 64);
  }
  float invD = 1.0f / 56.0f;
  float mean = sm * invD;
  float var = sq * invD - mean * mean;
  float rs = rsqrtf(var + 1e-5f);
  float r = (v - mean) * rs * g[lane < 56 ? lane : 0] + b[lane < 56 ? lane : 0];
  if (lane < 32) xsb[(size_t)n * 32 + lane] = f2bf(r);
  else if (lane < 56) xvf[(size_t)n * 24 + lane - 32] = r;
}

// ---------- block-1 message: Wedge-in-LDS V path + MFMA P-dot (register redistribute) ----------
__global__ __launch_bounds__(256) void k_msg1f(
    const int* __restrict__ esrc, const float* __restrict__ sh, const ushort16* __restrict__ hb,
    const ushort16* __restrict__ Pb, const float* __restrict__ xv,
    const ushort16* __restrict__ Bpw, ushort16* __restrict__ msg) {
  __shared__ ushort16 Wlds[16][392];   // padded: row stride 784B breaks bank alignment
  int w = threadIdx.x >> 6, lane = threadIdx.x & 63;
  int e0 = __builtin_amdgcn_readfirstlane(blockIdx.x * 16);
  int row = lane & 15, q = lane >> 4;
  // ---- phase 1: Wlds = h1b[16 rows] @ Bpw via 24 MFMA ----
  short8 a1 = *reinterpret_cast<const short8*>(hb + (size_t)(e0 + row) * 32 + q * 8);
  floatx4 zero = {0.f, 0.f, 0.f, 0.f};
#pragma unroll
  for (int t6 = 0; t6 < 6; ++t6) {
    int T = w * 6 + t6;
    short8 b1 = *reinterpret_cast<const short8*>(Bpw + (size_t)T * 512 + lane * 8);
    floatx4 acc = __builtin_amdgcn_mfma_f32_16x16x32_bf16(a1, b1, zero, 0, 0, 0);
#pragma unroll
    for (int r = 0; r < 4; ++r)
      Wlds[q * 4 + r][T * 16 + row] = f2bf(acc[r]);
  }
  __syncthreads();   // only barrier: Wlds complete
  // ---- phase 2: 4 edges per wave, lane owns channel; P-dot on MFMA ----
  int lv = lane - 32;
  int vq = (lv >= 0) ? ((lv / 3 > 7) ? 7 : lv / 3) : 0;  // v index for vector channels
  int vi = (lv >= 0) ? (lv - (lv / 3) * 3) : 0;          // component i
  int c2 = 32 + row; if (c2 > 39) c2 = 39;
#pragma unroll
  for (int k = 0; k < 4; ++k) {
    int e = e0 + w * 4 + k;
    int s = __builtin_amdgcn_readfirstlane(esrc[e]);
    float sh0 = sh[e * 3 + 0], sh1 = sh[e * 3 + 1], sh2 = sh[e * 3 + 2];
    const float* xr = xv + (size_t)s * 24;   // wave-uniform -> s_load broadcast
    const ushort16* wp = &Wlds[w * 4 + k][0];
    float vterm, mult;
    if (lane < 32) {
      mult = 1.0f;
      uint4 wv = *reinterpret_cast<const uint4*>(wp + lane * 8);
      float ww[8] = {bflo(wv.x), bfhi(wv.x), bflo(wv.y), bfhi(wv.y),
                     bflo(wv.z), bfhi(wv.z), bflo(wv.w), bfhi(wv.w)};
      vterm = 0.f;
#pragma unroll
      for (int u = 0; u < 8; ++u) {
        float du = K_DOT * (xr[u * 3] * sh0 + xr[u * 3 + 1] * sh1 + xr[u * 3 + 2] * sh2);
        vterm += du * ww[u];
      }
    } else {
      float shi = (vi == 0) ? sh0 : (vi == 1) ? sh1 : sh2;
      float s1 = (vi == 0) ? sh1 : (vi == 1) ? sh2 : sh0;   // sh[(vi+1)%3]
      float s2 = (vi == 0) ? sh2 : (vi == 1) ? sh0 : sh1;   // sh[(vi+2)%3]
      mult = shi;
      uint4 wvs = *reinterpret_cast<const uint4*>(wp + 256 + vq * 8);
      uint4 wvv = *reinterpret_cast<const uint4*>(wp + 320 + vq * 8);
      float vsw[8] = {bflo(wvs.x), bfhi(wvs.x), bflo(wvs.y), bfhi(wvs.y),
                      bflo(wvs.z), bfhi(wvs.z), bflo(wvs.w), bfhi(wvs.w)};
      float vvw[8] = {bflo(wvv.x), bfhi(wvv.x), bflo(wvv.y), bfhi(wvv.y),
                      bflo(wvv.z), bfhi(wvv.z), bflo(wvv.w), bfhi(wvv.w)};
      vterm = 0.f;
#pragma unroll
      for (int u = 0; u < 8; ++u) {
        float xu0 = xr[u * 3], xu1 = xr[u * 3 + 1], xu2 = xr[u * 3 + 2];
        float xui = (vi == 0) ? xu0 : (vi == 1) ? xu1 : xu2;
        float xi1 = (vi == 0) ? xu1 : (vi == 1) ? xu2 : xu0;  // xv[(vi+1)%3]
        float xi2 = (vi == 0) ? xu2 : (vi == 1) ? xu0 : xu1;  // xv[(vi+2)%3]
        float crs = xi1 * s2 - xi2 * s1;                       // cross(xv_u, sh)[vi]
        vterm += xui * vsw[u] + crs * vvw[u];
      }
    }
    // P path via MFMA: 3 tiles of 16 channels; redistribute in registers
    short8 af = *reinterpret_cast<const short8*>(hb + (size_t)e * 32 + q * 8);
    const ushort16* Pr = Pb + (size_t)s * 1280;
    short8 bf0 = *reinterpret_cast<const short8*>(Pr + row * 32 + q * 8);
    short8 bf1 = *reinterpret_cast<const short8*>(Pr + (16 + row) * 32 + q * 8);
    short8 bf2 = *reinterpret_cast<const short8*>(Pr + c2 * 32 + q * 8);
    floatx4 p0 = __builtin_amdgcn_mfma_f32_16x16x32_bf16(af, bf0, zero, 0, 0, 0);
    floatx4 p1 = __builtin_amdgcn_mfma_f32_16x16x32_bf16(af, bf1, zero, 0, 0, 0);
    floatx4 p2 = __builtin_amdgcn_mfma_f32_16x16x32_bf16(af, bf2, zero, 0, 0, 0);
    float pv2 = __shfl(p2[0], vq, 64);
    float pdot = (lane < 16) ? p0[0] : (lane < 32) ? p1[0] : pv2;
    if (lane < 56) msg[(size_t)e * 56 + lane] = f2bf(pdot * mult + vterm);
  }
}

// ---------- fused block-2 gather: per dst node, inline P-dot + vvs via MFMA + LN + out ----------
__global__ __launch_bounds__(256) void k_gather2(
    const int* __restrict__ deg, const int* __restrict__ eidx,
    const int* __restrict__ esrc, const float* __restrict__ sh,
    const ushort16* __restrict__ hb, const ushort16* __restrict__ Pb,
    const float* __restrict__ xv, const ushort16* __restrict__ Bpw,
    const float* __restrict__ g, const float* __restrict__ b,
    float* __restrict__ outf) {
  int n = __builtin_amdgcn_readfirstlane(blockIdx.x * 4 + (threadIdx.x >> 6));
  int lane = threadIdx.x & 63;
  int row = lane & 15, q = lane >> 4;
  int cnt = deg[n]; if (cnt > 64) cnt = 64;
  const int* ep = eidx + (size_t)n * 64;
  floatx4 zero = {0.f, 0.f, 0.f, 0.f};
  // hoist the 8 edge-invariant vvs B-fragments (u-major pack): 32 VGPRs
  short8 Bw[8];
#pragma unroll
  for (int u = 0; u < 8; ++u)
    Bw[u] = *reinterpret_cast<const short8*>(Bpw + (size_t)u * 512 + lane * 8);
  float v = 0.f;
  for (int j = 0; j < cnt; ++j) {
    int e = __builtin_amdgcn_readfirstlane(ep[j]);
    int s = __builtin_amdgcn_readfirstlane(esrc[e]);
    float sh0 = sh[e * 3 + 0], sh1 = sh[e * 3 + 1], sh2 = sh[e * 3 + 2];
    const float* xr = xv + (size_t)s * 24;    // wave-uniform -> SGPR broadcast
    float du[8];
#pragma unroll
    for (int u = 0; u < 8; ++u)
      du[u] = K_DOT * (xr[u * 3] * sh0 + xr[u * 3 + 1] * sh1 + xr[u * 3 + 2] * sh2);
    short8 af = *reinterpret_cast<const short8*>(hb + (size_t)e * 32 + q * 8);
    short8 bf = *reinterpret_cast<const short8*>(Pb + (size_t)s * 512 + row * 32 + q * 8);
    floatx4 p0 = __builtin_amdgcn_mfma_f32_16x16x32_bf16(af, bf, zero, 0, 0, 0);
    float acc = p0[0];   // lane L: P-dot for channel L&15 (rows identical)
#pragma unroll
    for (int u = 0; u < 8; ++u) {
      floatx4 wD = __builtin_amdgcn_mfma_f32_16x16x32_bf16(af, Bw[u], zero, 0, 0, 0);
      acc += du[u] * wD[0];   // lane L: w2[L&15][u]
    }
    v += acc;
  }
  // LN over 16 channels; all 64 lanes hold 4 identical replicas -> invD = 1/64 works
  v *= K_PRELN;
  float sm = v, sq = v * v;
#pragma unroll
  for (int off = 32; off > 0; off >>= 1) {
    sm += __shfl_xor(sm, off, 64);
    sq += __shfl_xor(sq, off, 64);
  }
  float invD = 1.0f / 64.0f;
  float mean = sm * invD;
  float var = sq * invD - mean * mean;
  float rs = rsqrtf(var + 1e-5f);
  float r = (v - mean) * rs * g[lane & 15] + b[lane & 15];
  if (lane < 16) outf[(size_t)n * 16 + lane] = r;
}

// ---------- bucket gather + LayerNorm: one wave per node ----------
__global__ __launch_bounds__(256) void k_gather_ln(
    const int* __restrict__ deg, const int* __restrict__ eidx,
    const ushort16* __restrict__ msg, int D,
    const float* __restrict__ g, const float* __restrict__ b,
    ushort16* __restrict__ xsb, float* __restrict__ xvf, float* __restrict__ outf) {
  int n = __builtin_amdgcn_readfirstlane(blockIdx.x * 4 + (threadIdx.x >> 6));
  int lane = threadIdx.x & 63;
  int cnt = deg[n]; if (cnt > 64) cnt = 64;
  const int* ep = eidx + (size_t)n * 64;
  float v = 0.f;
  for (int j = 0; j < cnt; ++j) {
    int e = ep[j];
    if (lane < D) v += bfs(msg[(size_t)e * D + lane]);
  }
  v *= K_PRELN;
  if (lane >= D) v = 0.f;
  float sm = v, sq = v * v;
#pragma unroll
  for (int off = 32; off > 0; off >>= 1) {
    sm += __shfl_xor(sm, off, 64);
    sq += __shfl_xor(sq, off, 64);
  }
  float invD = 1.0f / (float)D;
  float mean = sm * invD;
  float var = sq * invD - mean * mean;
  float rs = rsqrtf(var + 1e-5f);
  float r = (v - mean) * rs * g[lane < D ? lane : 0] + b[lane < D ? lane : 0];
  if (outf) {
    if (lane < D) outf[(size_t)n * D + lane] = r;
  } else {
    if (lane < 32) xsb[(size_t)n * 32 + lane] = f2bf(r);
    else if (lane < 56) xvf[(size_t)n * 24 + lane - 32] = r;
  }
}

extern "C" void kernel_launch(void* const* d_in, const int* in_sizes, int n_in,
                              void* d_out, int out_size, void* d_ws, size_t ws_size,
                              hipStream_t stream) {
  const float* pos = (const float*)d_in[0];
  const int* z = (const int*)d_in[1];
  const int* mol = (const int*)d_in[2];
  const int* esrc = (const int*)d_in[3];
  const int* edst = (const int*)d_in[4];
  const float* Ez = (const float*)d_in[5];
  const float* Em = (const float*)d_in[6];
  const float* b0W1 = (const float*)d_in[7];
  const float* b0W2 = (const float*)d_in[8];
  const float* b0g = (const float*)d_in[9];
  const float* b0b = (const float*)d_in[10];
  const float* b1W1 = (const float*)d_in[11];
  const float* b1W2 = (const float*)d_in[12];
  const float* b1g = (const float*)d_in[13];
  const float* b1b = (const float*)d_in[14];
  const float* b2W1 = (const float*)d_in[15];
  const float* b2W2 = (const float*)d_in[16];
  const float* b2g = (const float*)d_in[17];
  const float* b2b = (const float*)d_in[18];
  float* out = (float*)d_out;

  float* ws = (float*)d_ws;
  size_t o = 0;
  int* combo = (int*)(ws + o); o += NNODES;
  int* deg = (int*)(ws + o); o += NNODES;
  int* eidx = (int*)(ws + o); o += (size_t)NNODES * 64;  // fixed-capacity buckets
  ushort16* X0cb = (ushort16*)(ws + o); o += 8192;       // 256x64 bf16
  ushort16* xs1b = (ushort16*)(ws + o); o += 131072;     // 8192x32 bf16
  float* xv1 = ws + o; o += (size_t)NNODES * 24;         // 8192x24 f32
  ushort16* h0b = (ushort16*)(ws + o); o += (size_t)NEDGES * 16;   // 65536x32 bf16
  ushort16* h1b = (ushort16*)(ws + o); o += (size_t)NEDGES * 16;
  ushort16* h2b = (ushort16*)(ws + o); o += (size_t)NEDGES * 16;
  float* shb = ws + o; o += (size_t)NEDGES * 3;
  ushort16* Bp0 = (ushort16*)(ws + o); o += 40960;       // 80x2x512 bf16
  ushort16* Bp1 = (ushort16*)(ws + o); o += 20480;       // 80x512 bf16
  ushort16* Bp2 = (ushort16*)(ws + o); o += 8192;        // 32x512 bf16
  ushort16* Bpw1 = (ushort16*)(ws + o); o += 6144;       // 24x512 bf16
  ushort16* Bpw2 = (ushort16*)(ws + o); o += 2048;       // 8x512 bf16
  ushort16* P12 = (ushort16*)(ws + o); o += (size_t)NNODES * 640;  // 8192x1280 bf16
  ushort16* msgb = (ushort16*)(ws + o); o += (size_t)NEDGES * 28;  // 65536x56 bf16 (7.3 MB)

  ushort16* P0c = P12;          // 256x1280 bf16, consumed (gather0) before gemm1 overwrites
  ushort16* xs2b = xs1b;        // xs1b dead after gemm P12-1
  float* xv2 = xv1;             // xv1 dead after k_msg1f

  hipMemsetAsync(deg, 0, NNODES * sizeof(int), stream);

  k_prep<<<1472, 256, 0, stream>>>(pos, z, mol, esrc, edst, Ez, Em,
                                   b0W1, b1W1, b2W1, b0W2, b1W2, b2W2,
                                   combo, X0cb, shb, h0b, h1b, h2b,
                                   Bp0, Bp1, Bp2, Bpw1, Bpw2, deg, eidx);

  // block 0 (msg fused into gather: inline MFMA P-dot per incoming edge)
  k_gemm_mfma<<<dim3(4, 20), 256, 0, stream>>>(X0cb, Bp0, P0c, 1280, 64);
  k_gather0<<<2048, 256, 0, stream>>>(deg, eidx, combo, esrc, shb, h0b, P0c,
                                      b0g, b0b, xs1b, xv1);

  // block 1 (Wedge computed in-LDS inside k_msg1f)
  k_gemm_mfma<<<dim3(128, 20), 256, 0, stream>>>(xs1b, Bp1, P12, 1280, 32);
  k_msg1f<<<4096, 256, 0, stream>>>(esrc, shb, h1b, P12, xv1, Bpw1, msgb);
  k_gather_ln<<<2048, 256, 0, stream>>>(deg, eidx, msgb, 56, b1g, b1b, xs2b, xv2, nullptr);

  // block 2 (msg + gather + LN fully fused, vvs weights via broadcast-A MFMA)
  k_gemm_mfma<<<dim3(128, 8), 256, 0, stream>>>(xs2b, Bp2, P12, 512, 32);
  k_gather2<<<2048, 256, 0, stream>>>(deg, eidx, esrc, shb, h2b, P12, xv2, Bpw2,
                                      b2g, b2b, out);
}

// Round 14
// 205.302 us; speedup vs baseline: 1.0397x; 1.0397x over previous
//
#include <hip/hip_runtime.h>

#define NNODES 8192
#define NEDGES 65536

#define K_PACK   0.02209708691f   // 1/sqrt(2048)
#define K_P1SV   0.01804219593f   // 1/(32*sqrt3)
#define K_VVS    0.04419417382f   // 1/sqrt(512)
#define K_VS     0.03608439182f   // 1/(16*sqrt3)
#define K_VVV    0.02551551815f   // K_VS/sqrt2
#define K_DOT    0.57735026919f
#define K_PRELN  0.35355339059f
#define C_EMB    8.4335730689f

typedef unsigned int uint32;
typedef unsigned short ushort16;
typedef __attribute__((ext_vector_type(8))) short short8;
typedef __attribute__((ext_vector_type(4))) float floatx4;

__device__ __forceinline__ float siluf(float x) { return x / (1.0f + __expf(-x)); }
__device__ __forceinline__ float susf(float t) { return t > 0.0f ? __expf(-1.0f / t) : 0.0f; }
__device__ __forceinline__ ushort16 f2bf(float f) {
  uint32 u = __float_as_uint(f);
  return (ushort16)((u + 0x7fffu + ((u >> 16) & 1u)) >> 16);
}
__device__ __forceinline__ float bflo(uint32 v) { return __uint_as_float(v << 16); }
__device__ __forceinline__ float bfhi(uint32 v) { return __uint_as_float(v & 0xffff0000u); }
__device__ __forceinline__ float bfs(ushort16 v) { return __uint_as_float((uint32)v << 16); }

// ---------- prep: edge geom + 3 MLPs (split across 3x blocks, W in LDS), CSR, packs ----------
__global__ __launch_bounds__(256) void k_prep(
    const float* __restrict__ pos, const int* __restrict__ z, const int* __restrict__ mol,
    const int* __restrict__ esrc, const int* __restrict__ edst,
    const float* __restrict__ Ez, const float* __restrict__ Em,
    const float* __restrict__ W10, const float* __restrict__ W11, const float* __restrict__ W12,
    const float* __restrict__ W20, const float* __restrict__ W21, const float* __restrict__ W22,
    int* __restrict__ combo, ushort16* __restrict__ X0cb, float* __restrict__ sh,
    ushort16* __restrict__ h0b, ushort16* __restrict__ h1b, ushort16* __restrict__ h2b,
    ushort16* __restrict__ Bp0, ushort16* __restrict__ Bp1, ushort16* __restrict__ Bp2,
    ushort16* __restrict__ Bpw1, ushort16* __restrict__ Bpw2,
    int* __restrict__ deg, int* __restrict__ eidx) {
  __shared__ float Wl[320];
  int b = blockIdx.x;
  if (b < 768) {
    // ---- edge MLP phase: which = 0,1,2 ; 256 blocks each ----
    int which = b >> 8;
    int e = ((b & 255) << 8) + threadIdx.x;
    const float* W = (which == 0) ? W10 : (which == 1) ? W11 : W12;
    for (int i = threadIdx.x; i < 320; i += 256) Wl[i] = W[i];
    __syncthreads();
    int s = esrc[e], d = edst[e];
    float vx = pos[d * 3 + 0] - pos[s * 3 + 0];
    float vy = pos[d * 3 + 1] - pos[s * 3 + 1];
    float vz = pos[d * 3 + 2] - pos[s * 3 + 2];
    float len = sqrtf(vx * vx + vy * vy + vz * vz);
    if (which == 0) {
      int p = atomicAdd(&deg[d], 1);
      if (p < 64) eidx[(size_t)d * 64 + p] = e;
      float inv = 1.7320508076f / fmaxf(len, 1e-9f);
      sh[e * 3 + 0] = vx * inv; sh[e * 3 + 1] = vy * inv; sh[e * 3 + 2] = vz * inv;
    }
    float emb[10];
#pragma unroll
    for (int k = 0; k < 10; ++k) {
      float u = len * 1.1f - (float)(k + 1);
      emb[k] = C_EMB * susf(u + 1.0f) * susf(1.0f - u);
    }
    float H[32];
#pragma unroll
    for (int m = 0; m < 32; ++m) {
      float t = 0.f;
#pragma unroll
      for (int k = 0; k < 10; ++k) t += emb[k] * Wl[k * 32 + m];
      H[m] = siluf(t);
    }
    ushort16* hb = (which == 0) ? h0b : (which == 1) ? h1b : h2b;
    uint32* hp = (uint32*)(hb + (size_t)e * 32);
#pragma unroll
    for (int m = 0; m < 16; ++m)
      hp[m] = (uint32)f2bf(H[2 * m]) | ((uint32)f2bf(H[2 * m + 1]) << 16);
    return;
  }
  int idx = (b - 768) * 256 + threadIdx.x;
  if (idx < NNODES) { combo[idx] = z[idx] * 2 + mol[idx]; return; }
  idx -= NNODES;
  if (idx < 16384) {  // X0cb[256][64] bf16
    int c = idx >> 6, j = idx & 63;
    float v = 0.f;
    if (c < 200) {
      int zz = c >> 1, mm = c & 1;
      v = (j < 48) ? Ez[zz * 48 + j] : Em[mm * 16 + (j - 48)];
    }
    X0cb[idx] = f2bf(v);
    return;
  }
  idx -= 16384;
  if (idx < 81920) {  // Bp0[tile(80)][kh(2)][lane(64)][j(8)] bf16, K=64
    int tile = idx >> 10; int r = idx & 1023;
    int kh = r >> 9; int rr = r & 511;
    int lane = rr >> 3, j = rr & 7;
    int k = kh * 32 + (lane >> 4) * 8 + j;
    int n = tile * 16 + (lane & 15);
    int c = n >> 5, m = n & 31;
    int col = (c < 32) ? (k * 32 + c) : (2048 + k * 8 + (c - 32));
    Bp0[idx] = f2bf(W20[m * 2560 + col] * K_PACK);
    return;
  }
  idx -= 81920;
  if (idx < 40960) {  // Bp1[tile(80)][lane][j] bf16, K=32
    int tile = idx >> 9; int rr = idx & 511;
    int lane = rr >> 3, j = rr & 7;
    int k = (lane >> 4) * 8 + j;
    int n = tile * 16 + (lane & 15);
    int c = n >> 5, m = n & 31;
    float v = (c < 32) ? W21[m * 1664 + k * 32 + c] * K_PACK
                       : W21[m * 1664 + 1280 + k * 8 + (c - 32)] * K_P1SV;
    Bp1[idx] = f2bf(v);
    return;
  }
  idx -= 40960;
  if (idx < 16384) {  // Bp2[tile(32)][lane][j] bf16, K=32
    int tile = idx >> 9; int rr = idx & 511;
    int lane = rr >> 3, j = rr & 7;
    int k = (lane >> 4) * 8 + j;
    int n = tile * 16 + (lane & 15);
    int c = n >> 5, m = n & 31;
    Bp2[idx] = f2bf(W22[m * 640 + k * 16 + c] * K_PACK);
    return;
  }
  idx -= 16384;
  if (idx < 12288) {  // Bpw1: col n = c*8+u (vvs) | 256+vo*8+u (vs) | 320+vo*8+u (vvv)
    int tile = idx >> 9; int rr = idx & 511;
    int lane = rr >> 3, j = rr & 7;
    int m = (lane >> 4) * 8 + j;
    int n = tile * 16 + (lane & 15);
    float v;
    if (n < 256) {
      int c = n >> 3, u = n & 7;
      v = W21[m * 1664 + 1024 + u * 32 + c] * K_VVS;
    } else if (n < 320) {
      int vo = (n - 256) >> 3, u = n & 7;
      v = W21[m * 1664 + 1536 + u * 8 + vo] * K_VS;
    } else {
      int vo = (n - 320) >> 3, u = n & 7;
      v = W21[m * 1664 + 1600 + u * 8 + vo] * K_VVV;
    }
    Bpw1[idx] = f2bf(v);
    return;
  }
  idx -= 12288;
  {  // Bpw2: col n = c*8+u -> W22 vvs weights (c-major)
    int tile = idx >> 9; int rr = idx & 511;
    int lane = rr >> 3, j = rr & 7;
    int m = (lane >> 4) * 8 + j;
    int n = tile * 16 + (lane & 15);
    int c = n >> 3, u = n & 7;
    Bpw2[idx] = f2bf(W22[m * 640 + 512 + u * 16 + c] * K_VVS);
  }
}

// ---------- MFMA GEMM tile body ----------
__device__ __forceinline__ void gemm_tile(
    const ushort16* __restrict__ A, const ushort16* __restrict__ Bp, ushort16* __restrict__ C,
    int N, int K, int bx, int by, int wave, int lane) {
  int m0 = bx * 64 + wave * 16;
  int n0 = by * 64;
  int row = lane & 15, q = lane >> 4;
  int nkh = K >> 5;
  floatx4 acc[4];
  floatx4 zero = {0.f, 0.f, 0.f, 0.f};
#pragma unroll
  for (int t = 0; t < 4; ++t) acc[t] = zero;
  for (int kh = 0; kh < nkh; ++kh) {
    short8 a = *reinterpret_cast<const short8*>(A + (size_t)(m0 + row) * K + kh * 32 + q * 8);
#pragma unroll
    for (int t = 0; t < 4; ++t) {
      int T = (n0 >> 4) + t;
      short8 b = *reinterpret_cast<const short8*>(Bp + ((size_t)T * nkh + kh) * 512 + lane * 8);
      acc[t] = __builtin_amdgcn_mfma_f32_16x16x32_bf16(a, b, acc[t], 0, 0, 0);
    }
  }
  int colb = n0 + row;
#pragma unroll
  for (int t = 0; t < 4; ++t)
#pragma unroll
    for (int r = 0; r < 4; ++r)
      C[(size_t)(m0 + q * 4 + r) * N + colb + t * 16] = f2bf(acc[t][r]);
}

__global__ __launch_bounds__(256) void k_gemm_mfma(
    const ushort16* __restrict__ A, const ushort16* __restrict__ Bp, ushort16* __restrict__ C,
    int N, int K) {
  gemm_tile(A, Bp, C, N, K, blockIdx.x, blockIdx.y, threadIdx.x >> 6, threadIdx.x & 63);
}

// ---------- fused block-0 gather: per dst node, inline MFMA P-dot over incoming edges + LN ----------
__global__ __launch_bounds__(256) void k_gather0(
    const int* __restrict__ deg, const int* __restrict__ eidx,
    const int* __restrict__ combo, const int* __restrict__ esrc,
    const float* __restrict__ sh, const ushort16* __restrict__ hb,
    const ushort16* __restrict__ Pb,
    const float* __restrict__ g, const float* __restrict__ b,
    ushort16* __restrict__ xsb, float* __restrict__ xvf) {
  int n = __builtin_amdgcn_readfirstlane(blockIdx.x * 4 + (threadIdx.x >> 6));
  int lane = threadIdx.x & 63;
  int row = lane & 15, q = lane >> 4;
  int cnt = deg[n]; if (cnt > 64) cnt = 64;
  const int* ep = eidx + (size_t)n * 64;
  int lv = lane - 32;
  int vq = (lv >= 0) ? ((lv / 3 > 7) ? 7 : lv / 3) : 0;
  int vi = (lv >= 0) ? (lv - (lv / 3) * 3) : 0;
  int c2 = 32 + row; if (c2 > 39) c2 = 39;
  floatx4 zero = {0.f, 0.f, 0.f, 0.f};
  float v = 0.f;
  for (int j = 0; j < cnt; ++j) {
    int e = __builtin_amdgcn_readfirstlane(ep[j]);
    int s = __builtin_amdgcn_readfirstlane(esrc[e]);
    int rp = __builtin_amdgcn_readfirstlane(combo[s]);
    float sh0 = sh[e * 3 + 0], sh1 = sh[e * 3 + 1], sh2 = sh[e * 3 + 2];
    short8 af = *reinterpret_cast<const short8*>(hb + (size_t)e * 32 + q * 8);
    const ushort16* Pr = Pb + (size_t)rp * 1280;
    short8 bf0 = *reinterpret_cast<const short8*>(Pr + row * 32 + q * 8);
    short8 bf1 = *reinterpret_cast<const short8*>(Pr + (16 + row) * 32 + q * 8);
    short8 bf2 = *reinterpret_cast<const short8*>(Pr + c2 * 32 + q * 8);
    floatx4 p0 = __builtin_amdgcn_mfma_f32_16x16x32_bf16(af, bf0, zero, 0, 0, 0);
    floatx4 p1 = __builtin_amdgcn_mfma_f32_16x16x32_bf16(af, bf1, zero, 0, 0, 0);
    floatx4 p2 = __builtin_amdgcn_mfma_f32_16x16x32_bf16(af, bf2, zero, 0, 0, 0);
    // broadcast-A MFMA: lane L holds channel (L&15) of each tile in reg 0
    float pv2 = __shfl(p2[0], vq, 64);
    float pdot = (lane < 16) ? p0[0] : (lane < 32) ? p1[0] : pv2;
    float mult = (lane < 32) ? 1.0f : ((vi == 0) ? sh0 : (vi == 1) ? sh1 : sh2);
    v += pdot * mult;
  }
  v *= K_PRELN;
  if (lane >= 56) v = 0.f;
  float sm = v, sq = v * v;
#pragma unroll
  for (int off = 32; off > 0; off >>= 1) {
    sm += __shfl_xor(sm, off, 64);
    sq += __shfl_xor(sq, off, 64);
  }
  float invD = 1.0f / 56.0f;
  float mean = sm * invD;
  float var = sq * invD - mean * mean;
  float rs = rsqrtf(var + 1e-5f);
  float r = (v - mean) * rs * g[lane < 56 ? lane : 0] + b[lane < 56 ? lane : 0];
  if (lane < 32) xsb[(size_t)n * 32 + lane] = f2bf(r);
  else if (lane < 56) xvf[(size_t)n * 24 + lane - 32] = r;
}

// ---------- block-1 message: Wedge-in-LDS V path + MFMA P-dot (register redistribute) ----------
__global__ __launch_bounds__(256) void k_msg1f(
    const int* __restrict__ esrc, const float* __restrict__ sh, const ushort16* __restrict__ hb,
    const ushort16* __restrict__ Pb, const float* __restrict__ xv,
    const ushort16* __restrict__ Bpw, ushort16* __restrict__ msg) {
  __shared__ ushort16 Wlds[16][392];   // padded: row stride 784B breaks bank alignment
  int w = threadIdx.x >> 6, lane = threadIdx.x & 63;
  int e0 = __builtin_amdgcn_readfirstlane(blockIdx.x * 16);
  int row = lane & 15, q = lane >> 4;
  // ---- phase 1: Wlds = h1b[16 rows] @ Bpw via 24 MFMA ----
  short8 a1 = *reinterpret_cast<const short8*>(hb + (size_t)(e0 + row) * 32 + q * 8);
  floatx4 zero = {0.f, 0.f, 0.f, 0.f};
#pragma unroll
  for (int t6 = 0; t6 < 6; ++t6) {
    int T = w * 6 + t6;
    short8 b1 = *reinterpret_cast<const short8*>(Bpw + (size_t)T * 512 + lane * 8);
    floatx4 acc = __builtin_amdgcn_mfma_f32_16x16x32_bf16(a1, b1, zero, 0, 0, 0);
#pragma unroll
    for (int r = 0; r < 4; ++r)
      Wlds[q * 4 + r][T * 16 + row] = f2bf(acc[r]);
  }
  __syncthreads();   // only barrier: Wlds complete
  // ---- phase 2: 4 edges per wave, lane owns channel; P-dot on MFMA ----
  int lv = lane - 32;
  int vq = (lv >= 0) ? ((lv / 3 > 7) ? 7 : lv / 3) : 0;  // v index for vector channels
  int vi = (lv >= 0) ? (lv - (lv / 3) * 3) : 0;          // component i
  int c2 = 32 + row; if (c2 > 39) c2 = 39;
#pragma unroll
  for (int k = 0; k < 4; ++k) {
    int e = e0 + w * 4 + k;
    int s = __builtin_amdgcn_readfirstlane(esrc[e]);
    float sh0 = sh[e * 3 + 0], sh1 = sh[e * 3 + 1], sh2 = sh[e * 3 + 2];
    const float* xr = xv + (size_t)s * 24;   // wave-uniform -> s_load broadcast
    const ushort16* wp = &Wlds[w * 4 + k][0];
    float vterm, mult;
    if (lane < 32) {
      mult = 1.0f;
      uint4 wv = *reinterpret_cast<const uint4*>(wp + lane * 8);
      float ww[8] = {bflo(wv.x), bfhi(wv.x), bflo(wv.y), bfhi(wv.y),
                     bflo(wv.z), bfhi(wv.z), bflo(wv.w), bfhi(wv.w)};
      // reassociated: a_i = sum_u xv[u][i]*w[u]; vterm = K_DOT*(a . sh)
      float a0 = 0.f, a1s = 0.f, a2 = 0.f;
#pragma unroll
      for (int u = 0; u < 8; ++u) {
        a0 += xr[u * 3 + 0] * ww[u];
        a1s += xr[u * 3 + 1] * ww[u];
        a2 += xr[u * 3 + 2] * ww[u];
      }
      vterm = K_DOT * (a0 * sh0 + a1s * sh1 + a2 * sh2);
    } else {
      float shi = (vi == 0) ? sh0 : (vi == 1) ? sh1 : sh2;
      float s1 = (vi == 0) ? sh1 : (vi == 1) ? sh2 : sh0;   // sh[(vi+1)%3]
      float s2 = (vi == 0) ? sh2 : (vi == 1) ? sh0 : sh1;   // sh[(vi+2)%3]
      mult = shi;
      uint4 wvs = *reinterpret_cast<const uint4*>(wp + 256 + vq * 8);
      uint4 wvv = *reinterpret_cast<const uint4*>(wp + 320 + vq * 8);
      float vsw[8] = {bflo(wvs.x), bfhi(wvs.x), bflo(wvs.y), bfhi(wvs.y),
                      bflo(wvs.z), bfhi(wvs.z), bflo(wvs.w), bfhi(wvs.w)};
      float vvw[8] = {bflo(wvv.x), bfhi(wvv.x), bflo(wvv.y), bfhi(wvv.y),
                      bflo(wvv.z), bfhi(wvv.z), bflo(wvv.w), bfhi(wvv.w)};
      // reassociated: cross term = s2*sum(xi1*vvw) - s1*sum(xi2*vvw)
      float b0 = 0.f, b1 = 0.f, b2 = 0.f;
#pragma unroll
      for (int u = 0; u < 8; ++u) {
        float xu0 = xr[u * 3], xu1 = xr[u * 3 + 1], xu2 = xr[u * 3 + 2];
        float xui = (vi == 0) ? xu0 : (vi == 1) ? xu1 : xu2;
        float xi1 = (vi == 0) ? xu1 : (vi == 1) ? xu2 : xu0;  // xv[(vi+1)%3]
        float xi2 = (vi == 0) ? xu2 : (vi == 1) ? xu0 : xu1;  // xv[(vi+2)%3]
        b0 += xui * vsw[u];
        b1 += xi1 * vvw[u];
        b2 += xi2 * vvw[u];
      }
      vterm = b0 + s2 * b1 - s1 * b2;
    }
    // P path via MFMA: 3 tiles of 16 channels; redistribute in registers
    short8 af = *reinterpret_cast<const short8*>(hb + (size_t)e * 32 + q * 8);
    const ushort16* Pr = Pb + (size_t)s * 1280;
    short8 bf0 = *reinterpret_cast<const short8*>(Pr + row * 32 + q * 8);
    short8 bf1 = *reinterpret_cast<const short8*>(Pr + (16 + row) * 32 + q * 8);
    short8 bf2 = *reinterpret_cast<const short8*>(Pr + c2 * 32 + q * 8);
    floatx4 p0 = __builtin_amdgcn_mfma_f32_16x16x32_bf16(af, bf0, zero, 0, 0, 0);
    floatx4 p1 = __builtin_amdgcn_mfma_f32_16x16x32_bf16(af, bf1, zero, 0, 0, 0);
    floatx4 p2 = __builtin_amdgcn_mfma_f32_16x16x32_bf16(af, bf2, zero, 0, 0, 0);
    float pv2 = __shfl(p2[0], vq, 64);
    float pdot = (lane < 16) ? p0[0] : (lane < 32) ? p1[0] : pv2;
    if (lane < 56) msg[(size_t)e * 56 + lane] = f2bf(pdot * mult + vterm);
  }
}

// ---------- block-2 message: Wedge-in-LDS V path + single-MFMA P-dot ----------
__global__ __launch_bounds__(256) void k_msg2f(
    const int* __restrict__ esrc, const float* __restrict__ sh, const ushort16* __restrict__ hb,
    const ushort16* __restrict__ Pb, const float* __restrict__ xv,
    const ushort16* __restrict__ Bpw, ushort16* __restrict__ msg) {
  __shared__ ushort16 Wlds[16][136];   // padded row stride 272B
  int w = threadIdx.x >> 6, lane = threadIdx.x & 63;
  int e0 = __builtin_amdgcn_readfirstlane(blockIdx.x * 16);
  int row = lane & 15, q = lane >> 4;
  // ---- phase 1: 8 tiles, 2 per wave ----
  short8 a1 = *reinterpret_cast<const short8*>(hb + (size_t)(e0 + row) * 32 + q * 8);
  floatx4 zero = {0.f, 0.f, 0.f, 0.f};
#pragma unroll
  for (int t2 = 0; t2 < 2; ++t2) {
    int T = w * 2 + t2;
    short8 b1 = *reinterpret_cast<const short8*>(Bpw + (size_t)T * 512 + lane * 8);
    floatx4 acc = __builtin_amdgcn_mfma_f32_16x16x32_bf16(a1, b1, zero, 0, 0, 0);
#pragma unroll
    for (int r = 0; r < 4; ++r)
      Wlds[q * 4 + r][T * 16 + row] = f2bf(acc[r]);
  }
  __syncthreads();
  // ---- phase 2: 4 edges per wave; V path shuffle-free, P via 1 MFMA ----
  int cch = lane & 15;   // this lane's output channel
#pragma unroll
  for (int k = 0; k < 4; ++k) {
    int e = e0 + w * 4 + k;
    int s = __builtin_amdgcn_readfirstlane(esrc[e]);
    float sh0 = sh[e * 3 + 0], sh1 = sh[e * 3 + 1], sh2 = sh[e * 3 + 2];
    const float* xr = xv + (size_t)s * 24;
    // V path: reassociated a_i = sum_u xv[u][i]*w[u]; vterm = K_DOT*(a . sh)
    uint4 wv = *reinterpret_cast<const uint4*>(&Wlds[w * 4 + k][0] + cch * 8);
    float ww[8] = {bflo(wv.x), bfhi(wv.x), bflo(wv.y), bfhi(wv.y),
                   bflo(wv.z), bfhi(wv.z), bflo(wv.w), bfhi(wv.w)};
    float a0 = 0.f, a1s = 0.f, a2 = 0.f;
#pragma unroll
    for (int u = 0; u < 8; ++u) {
      a0 += xr[u * 3 + 0] * ww[u];
      a1s += xr[u * 3 + 1] * ww[u];
      a2 += xr[u * 3 + 2] * ww[u];
    }
    float vterm = K_DOT * (a0 * sh0 + a1s * sh1 + a2 * sh2);
    // P path via one MFMA (16 channels)
    short8 af = *reinterpret_cast<const short8*>(hb + (size_t)e * 32 + q * 8);
    short8 bf = *reinterpret_cast<const short8*>(Pb + (size_t)s * 512 + row * 32 + q * 8);
    floatx4 p0 = __builtin_amdgcn_mfma_f32_16x16x32_bf16(af, bf, zero, 0, 0, 0);
    if (lane < 16) msg[(size_t)e * 16 + lane] = f2bf(p0[0] + vterm);
  }
}

// ---------- bucket gather + LayerNorm: one wave per node ----------
__global__ __launch_bounds__(256) void k_gather_ln(
    const int* __restrict__ deg, const int* __restrict__ eidx,
    const ushort16* __restrict__ msg, int D,
    const float* __restrict__ g, const float* __restrict__ b,
    ushort16* __restrict__ xsb, float* __restrict__ xvf, float* __restrict__ outf) {
  int n = __builtin_amdgcn_readfirstlane(blockIdx.x * 4 + (threadIdx.x >> 6));
  int lane = threadIdx.x & 63;
  int cnt = deg[n]; if (cnt > 64) cnt = 64;
  const int* ep = eidx + (size_t)n * 64;
  float v = 0.f;
  for (int j = 0; j < cnt; ++j) {
    int e = ep[j];
    if (lane < D) v += bfs(msg[(size_t)e * D + lane]);
  }
  v *= K_PRELN;
  if (lane >= D) v = 0.f;
  float sm = v, sq = v * v;
#pragma unroll
  for (int off = 32; off > 0; off >>= 1) {
    sm += __shfl_xor(sm, off, 64);
    sq += __shfl_xor(sq, off, 64);
  }
  float invD = 1.0f / (float)D;
  float mean = sm * invD;
  float var = sq * invD - mean * mean;
  float rs = rsqrtf(var + 1e-5f);
  float r = (v - mean) * rs * g[lane < D ? lane : 0] + b[lane < D ? lane : 0];
  if (outf) {
    if (lane < D) outf[(size_t)n * D + lane] = r;
  } else {
    if (lane < 32) xsb[(size_t)n * 32 + lane] = f2bf(r);
    else if (lane < 56) xvf[(size_t)n * 24 + lane - 32] = r;
  }
}

extern "C" void kernel_launch(void* const* d_in, const int* in_sizes, int n_in,
                              void* d_out, int out_size, void* d_ws, size_t ws_size,
                              hipStream_t stream) {
  const float* pos = (const float*)d_in[0];
  const int* z = (const int*)d_in[1];
  const int* mol = (const int*)d_in[2];
  const int* esrc = (const int*)d_in[3];
  const int* edst = (const int*)d_in[4];
  const float* Ez = (const float*)d_in[5];
  const float* Em = (const float*)d_in[6];
  const float* b0W1 = (const float*)d_in[7];
  const float* b0W2 = (const float*)d_in[8];
  const float* b0g = (const float*)d_in[9];
  const float* b0b = (const float*)d_in[10];
  const float* b1W1 = (const float*)d_in[11];
  const float* b1W2 = (const float*)d_in[12];
  const float* b1g = (const float*)d_in[13];
  const float* b1b = (const float*)d_in[14];
  const float* b2W1 = (const float*)d_in[15];
  const float* b2W2 = (const float*)d_in[16];
  const float* b2g = (const float*)d_in[17];
  const float* b2b = (const float*)d_in[18];
  float* out = (float*)d_out;

  float* ws = (float*)d_ws;
  size_t o = 0;
  int* combo = (int*)(ws + o); o += NNODES;
  int* deg = (int*)(ws + o); o += NNODES;
  int* eidx = (int*)(ws + o); o += (size_t)NNODES * 64;  // fixed-capacity buckets
  ushort16* X0cb = (ushort16*)(ws + o); o += 8192;       // 256x64 bf16
  ushort16* xs1b = (ushort16*)(ws + o); o += 131072;     // 8192x32 bf16
  float* xv1 = ws + o; o += (size_t)NNODES * 24;         // 8192x24 f32
  ushort16* h0b = (ushort16*)(ws + o); o += (size_t)NEDGES * 16;   // 65536x32 bf16
  ushort16* h1b = (ushort16*)(ws + o); o += (size_t)NEDGES * 16;
  ushort16* h2b = (ushort16*)(ws + o); o += (size_t)NEDGES * 16;
  float* shb = ws + o; o += (size_t)NEDGES * 3;
  ushort16* Bp0 = (ushort16*)(ws + o); o += 40960;       // 80x2x512 bf16
  ushort16* Bp1 = (ushort16*)(ws + o); o += 20480;       // 80x512 bf16
  ushort16* Bp2 = (ushort16*)(ws + o); o += 8192;        // 32x512 bf16
  ushort16* Bpw1 = (ushort16*)(ws + o); o += 6144;       // 24x512 bf16
  ushort16* Bpw2 = (ushort16*)(ws + o); o += 2048;       // 8x512 bf16
  ushort16* P12 = (ushort16*)(ws + o); o += (size_t)NNODES * 640;  // 8192x1280 bf16
  ushort16* msgb = (ushort16*)(ws + o); o += (size_t)NEDGES * 28;  // 65536x56 bf16 (7.3 MB)

  ushort16* P0c = P12;          // 256x1280 bf16, consumed (gather0) before gemm1 overwrites
  ushort16* xs2b = xs1b;        // xs1b dead after gemm P12-1
  float* xv2 = xv1;             // xv1 dead after k_msg1f
  ushort16* msg16 = msgb;       // block-1 msg dead after gather1

  hipMemsetAsync(deg, 0, NNODES * sizeof(int), stream);

  k_prep<<<1472, 256, 0, stream>>>(pos, z, mol, esrc, edst, Ez, Em,
                                   b0W1, b1W1, b2W1, b0W2, b1W2, b2W2,
                                   combo, X0cb, shb, h0b, h1b, h2b,
                                   Bp0, Bp1, Bp2, Bpw1, Bpw2, deg, eidx);

  // block 0 (msg fused into gather: inline MFMA P-dot per incoming edge)
  k_gemm_mfma<<<dim3(4, 20), 256, 0, stream>>>(X0cb, Bp0, P0c, 1280, 64);
  k_gather0<<<2048, 256, 0, stream>>>(deg, eidx, combo, esrc, shb, h0b, P0c,
                                      b0g, b0b, xs1b, xv1);

  // block 1 (Wedge computed in-LDS inside k_msg1f)
  k_gemm_mfma<<<dim3(128, 20), 256, 0, stream>>>(xs1b, Bp1, P12, 1280, 32);
  k_msg1f<<<4096, 256, 0, stream>>>(esrc, shb, h1b, P12, xv1, Bpw1, msgb);
  k_gather_ln<<<2048, 256, 0, stream>>>(deg, eidx, msgb, 56, b1g, b1b, xs2b, xv2, nullptr);

  // block 2
  k_gemm_mfma<<<dim3(128, 8), 256, 0, stream>>>(xs2b, Bp2, P12, 512, 32);
  k_msg2f<<<4096, 256, 0, stream>>>(esrc, shb, h2b, P12, xv2, Bpw2, msg16);
  k_gather_ln<<<2048, 256, 0, stream>>>(deg, eidx, msg16, 16, b2g, b2b, nullptr, nullptr, out);
}

// Round 15
// 202.304 us; speedup vs baseline: 1.0551x; 1.0148x over previous
//
#include <hip/hip_runtime.h>

#define NNODES 8192
#define NEDGES 65536

#define K_PACK   0.02209708691f   // 1/sqrt(2048)
#define K_P1SV   0.01804219593f   // 1/(32*sqrt3)
#define K_VVS    0.04419417382f   // 1/sqrt(512)
#define K_VS     0.03608439182f   // 1/(16*sqrt3)
#define K_VVV    0.02551551815f   // K_VS/sqrt2
#define K_DOT    0.57735026919f
#define K_PRELN  0.35355339059f
#define C_EMB    8.4335730689f

typedef unsigned int uint32;
typedef unsigned short ushort16;
typedef __attribute__((ext_vector_type(8))) short short8;
typedef __attribute__((ext_vector_type(4))) float floatx4;

__device__ __forceinline__ float siluf(float x) { return x / (1.0f + __expf(-x)); }
__device__ __forceinline__ float susf(float t) { return t > 0.0f ? __expf(-1.0f / t) : 0.0f; }
__device__ __forceinline__ ushort16 f2bf(float f) {
  uint32 u = __float_as_uint(f);
  return (ushort16)((u + 0x7fffu + ((u >> 16) & 1u)) >> 16);
}
__device__ __forceinline__ float bflo(uint32 v) { return __uint_as_float(v << 16); }
__device__ __forceinline__ float bfhi(uint32 v) { return __uint_as_float(v & 0xffff0000u); }
__device__ __forceinline__ float bfs(ushort16 v) { return __uint_as_float((uint32)v << 16); }

// ---------- prep: edge geom + 3 MLPs (split across 3x blocks, W in LDS), CSR, packs ----------
__global__ __launch_bounds__(256) void k_prep(
    const float* __restrict__ pos, const int* __restrict__ z, const int* __restrict__ mol,
    const int* __restrict__ esrc, const int* __restrict__ edst,
    const float* __restrict__ Ez, const float* __restrict__ Em,
    const float* __restrict__ W10, const float* __restrict__ W11, const float* __restrict__ W12,
    const float* __restrict__ W20, const float* __restrict__ W21, const float* __restrict__ W22,
    int* __restrict__ combo, ushort16* __restrict__ X0cb, float* __restrict__ sh,
    ushort16* __restrict__ h0b, ushort16* __restrict__ h1b, ushort16* __restrict__ h2b,
    ushort16* __restrict__ Bp0, ushort16* __restrict__ Bp1, ushort16* __restrict__ Bp2,
    ushort16* __restrict__ Bpw1, ushort16* __restrict__ Bpw2,
    int* __restrict__ deg, int* __restrict__ eidx) {
  __shared__ float Wl[320];
  int b = blockIdx.x;
  if (b < 768) {
    // ---- edge MLP phase: which = 0,1,2 ; 256 blocks each ----
    int which = b >> 8;
    int e = ((b & 255) << 8) + threadIdx.x;
    const float* W = (which == 0) ? W10 : (which == 1) ? W11 : W12;
    for (int i = threadIdx.x; i < 320; i += 256) Wl[i] = W[i];
    __syncthreads();
    int s = esrc[e], d = edst[e];
    float vx = pos[d * 3 + 0] - pos[s * 3 + 0];
    float vy = pos[d * 3 + 1] - pos[s * 3 + 1];
    float vz = pos[d * 3 + 2] - pos[s * 3 + 2];
    float len = sqrtf(vx * vx + vy * vy + vz * vz);
    if (which == 0) {
      int p = atomicAdd(&deg[d], 1);
      if (p < 64) eidx[(size_t)d * 64 + p] = e;
      float inv = 1.7320508076f / fmaxf(len, 1e-9f);
      sh[e * 3 + 0] = vx * inv; sh[e * 3 + 1] = vy * inv; sh[e * 3 + 2] = vz * inv;
    }
    float emb[10];
#pragma unroll
    for (int k = 0; k < 10; ++k) {
      float u = len * 1.1f - (float)(k + 1);
      emb[k] = C_EMB * susf(u + 1.0f) * susf(1.0f - u);
    }
    float H[32];
#pragma unroll
    for (int m = 0; m < 32; ++m) {
      float t = 0.f;
#pragma unroll
      for (int k = 0; k < 10; ++k) t += emb[k] * Wl[k * 32 + m];
      H[m] = siluf(t);
    }
    ushort16* hb = (which == 0) ? h0b : (which == 1) ? h1b : h2b;
    uint32* hp = (uint32*)(hb + (size_t)e * 32);
#pragma unroll
    for (int m = 0; m < 16; ++m)
      hp[m] = (uint32)f2bf(H[2 * m]) | ((uint32)f2bf(H[2 * m + 1]) << 16);
    return;
  }
  int idx = (b - 768) * 256 + threadIdx.x;
  if (idx < NNODES) { combo[idx] = z[idx] * 2 + mol[idx]; return; }
  idx -= NNODES;
  if (idx < 16384) {  // X0cb[256][64] bf16
    int c = idx >> 6, j = idx & 63;
    float v = 0.f;
    if (c < 200) {
      int zz = c >> 1, mm = c & 1;
      v = (j < 48) ? Ez[zz * 48 + j] : Em[mm * 16 + (j - 48)];
    }
    X0cb[idx] = f2bf(v);
    return;
  }
  idx -= 16384;
  if (idx < 81920) {  // Bp0[tile(80)][kh(2)][lane(64)][j(8)] bf16, K=64
    int tile = idx >> 10; int r = idx & 1023;
    int kh = r >> 9; int rr = r & 511;
    int lane = rr >> 3, j = rr & 7;
    int k = kh * 32 + (lane >> 4) * 8 + j;
    int n = tile * 16 + (lane & 15);
    int c = n >> 5, m = n & 31;
    int col = (c < 32) ? (k * 32 + c) : (2048 + k * 8 + (c - 32));
    Bp0[idx] = f2bf(W20[m * 2560 + col] * K_PACK);
    return;
  }
  idx -= 81920;
  if (idx < 40960) {  // Bp1[tile(80)][lane][j] bf16, K=32
    int tile = idx >> 9; int rr = idx & 511;
    int lane = rr >> 3, j = rr & 7;
    int k = (lane >> 4) * 8 + j;
    int n = tile * 16 + (lane & 15);
    int c = n >> 5, m = n & 31;
    float v = (c < 32) ? W21[m * 1664 + k * 32 + c] * K_PACK
                       : W21[m * 1664 + 1280 + k * 8 + (c - 32)] * K_P1SV;
    Bp1[idx] = f2bf(v);
    return;
  }
  idx -= 40960;
  if (idx < 16384) {  // Bp2[tile(32)][lane][j] bf16, K=32
    int tile = idx >> 9; int rr = idx & 511;
    int lane = rr >> 3, j = rr & 7;
    int k = (lane >> 4) * 8 + j;
    int n = tile * 16 + (lane & 15);
    int c = n >> 5, m = n & 31;
    Bp2[idx] = f2bf(W22[m * 640 + k * 16 + c] * K_PACK);
    return;
  }
  idx -= 16384;
  if (idx < 12288) {  // Bpw1: col n = c*8+u (vvs) | 256+vo*8+u (vs) | 320+vo*8+u (vvv)
    int tile = idx >> 9; int rr = idx & 511;
    int lane = rr >> 3, j = rr & 7;
    int m = (lane >> 4) * 8 + j;
    int n = tile * 16 + (lane & 15);
    float v;
    if (n < 256) {
      int c = n >> 3, u = n & 7;
      v = W21[m * 1664 + 1024 + u * 32 + c] * K_VVS;
    } else if (n < 320) {
      int vo = (n - 256) >> 3, u = n & 7;
      v = W21[m * 1664 + 1536 + u * 8 + vo] * K_VS;
    } else {
      int vo = (n - 320) >> 3, u = n & 7;
      v = W21[m * 1664 + 1600 + u * 8 + vo] * K_VVV;
    }
    Bpw1[idx] = f2bf(v);
    return;
  }
  idx -= 12288;
  {  // Bpw2: col n = c*8+u -> W22 vvs weights (c-major)
    int tile = idx >> 9; int rr = idx & 511;
    int lane = rr >> 3, j = rr & 7;
    int m = (lane >> 4) * 8 + j;
    int n = tile * 16 + (lane & 15);
    int c = n >> 3, u = n & 7;
    Bpw2[idx] = f2bf(W22[m * 640 + 512 + u * 16 + c] * K_VVS);
  }
}

// ---------- MFMA GEMM tile body ----------
__device__ __forceinline__ void gemm_tile(
    const ushort16* __restrict__ A, const ushort16* __restrict__ Bp, ushort16* __restrict__ C,
    int N, int K, int bx, int by, int wave, int lane) {
  int m0 = bx * 64 + wave * 16;
  int n0 = by * 64;
  int row = lane & 15, q = lane >> 4;
  int nkh = K >> 5;
  floatx4 acc[4];
  floatx4 zero = {0.f, 0.f, 0.f, 0.f};
#pragma unroll
  for (int t = 0; t < 4; ++t) acc[t] = zero;
  for (int kh = 0; kh < nkh; ++kh) {
    short8 a = *reinterpret_cast<const short8*>(A + (size_t)(m0 + row) * K + kh * 32 + q * 8);
#pragma unroll
    for (int t = 0; t < 4; ++t) {
      int T = (n0 >> 4) + t;
      short8 b = *reinterpret_cast<const short8*>(Bp + ((size_t)T * nkh + kh) * 512 + lane * 8);
      acc[t] = __builtin_amdgcn_mfma_f32_16x16x32_bf16(a, b, acc[t], 0, 0, 0);
    }
  }
  int colb = n0 + row;
#pragma unroll
  for (int t = 0; t < 4; ++t)
#pragma unroll
    for (int r = 0; r < 4; ++r)
      C[(size_t)(m0 + q * 4 + r) * N + colb + t * 16] = f2bf(acc[t][r]);
}

__global__ __launch_bounds__(256) void k_gemm_mfma(
    const ushort16* __restrict__ A, const ushort16* __restrict__ Bp, ushort16* __restrict__ C,
    int N, int K) {
  gemm_tile(A, Bp, C, N, K, blockIdx.x, blockIdx.y, threadIdx.x >> 6, threadIdx.x & 63);
}

// ---------- fused block-0 gather: per dst node, inline MFMA P-dot; index chain pipelined ----------
__global__ __launch_bounds__(256) void k_gather0(
    const int* __restrict__ deg, const int* __restrict__ eidx,
    const int* __restrict__ combo, const int* __restrict__ esrc,
    const float* __restrict__ sh, const ushort16* __restrict__ hb,
    const ushort16* __restrict__ Pb,
    const float* __restrict__ g, const float* __restrict__ b,
    ushort16* __restrict__ xsb, float* __restrict__ xvf) {
  int n = __builtin_amdgcn_readfirstlane(blockIdx.x * 4 + (threadIdx.x >> 6));
  int lane = threadIdx.x & 63;
  int row = lane & 15, q = lane >> 4;
  int cnt = deg[n]; if (cnt > 64) cnt = 64;
  const int* ep = eidx + (size_t)n * 64;
  int lv = lane - 32;
  int vq = (lv >= 0) ? ((lv / 3 > 7) ? 7 : lv / 3) : 0;
  int vi = (lv >= 0) ? (lv - (lv / 3) * 3) : 0;
  int c2 = 32 + row; if (c2 > 39) c2 = 39;
  floatx4 zero = {0.f, 0.f, 0.f, 0.f};
  float v = 0.f;
  // 1-deep index-chain prefetch: e->s->rp for j+1 overlaps iteration j's P-loads/MFMA
  int e_n = 0, s_n = 0, rp_n = 0;
  if (cnt > 0) {
    e_n = __builtin_amdgcn_readfirstlane(ep[0]);
    s_n = __builtin_amdgcn_readfirstlane(esrc[e_n]);
    rp_n = __builtin_amdgcn_readfirstlane(combo[s_n]);
  }
  for (int j = 0; j < cnt; ++j) {
    int e = e_n, rp = rp_n;
    if (j + 1 < cnt) {
      e_n = __builtin_amdgcn_readfirstlane(ep[j + 1]);
      s_n = __builtin_amdgcn_readfirstlane(esrc[e_n]);
      rp_n = __builtin_amdgcn_readfirstlane(combo[s_n]);
    }
    float sh0 = sh[e * 3 + 0], sh1 = sh[e * 3 + 1], sh2 = sh[e * 3 + 2];
    short8 af = *reinterpret_cast<const short8*>(hb + (size_t)e * 32 + q * 8);
    const ushort16* Pr = Pb + (size_t)rp * 1280;
    short8 bf0 = *reinterpret_cast<const short8*>(Pr + row * 32 + q * 8);
    short8 bf1 = *reinterpret_cast<const short8*>(Pr + (16 + row) * 32 + q * 8);
    short8 bf2 = *reinterpret_cast<const short8*>(Pr + c2 * 32 + q * 8);
    floatx4 p0 = __builtin_amdgcn_mfma_f32_16x16x32_bf16(af, bf0, zero, 0, 0, 0);
    floatx4 p1 = __builtin_amdgcn_mfma_f32_16x16x32_bf16(af, bf1, zero, 0, 0, 0);
    floatx4 p2 = __builtin_amdgcn_mfma_f32_16x16x32_bf16(af, bf2, zero, 0, 0, 0);
    // broadcast-A MFMA: lane L holds channel (L&15) of each tile in reg 0
    float pv2 = __shfl(p2[0], vq, 64);
    float pdot = (lane < 16) ? p0[0] : (lane < 32) ? p1[0] : pv2;
    float mult = (lane < 32) ? 1.0f : ((vi == 0) ? sh0 : (vi == 1) ? sh1 : sh2);
    v += pdot * mult;
  }
  v *= K_PRELN;
  if (lane >= 56) v = 0.f;
  float sm = v, sq = v * v;
#pragma unroll
  for (int off = 32; off > 0; off >>= 1) {
    sm += __shfl_xor(sm, off, 64);
    sq += __shfl_xor(sq, off, 64);
  }
  float invD = 1.0f / 56.0f;
  float mean = sm * invD;
  float var = sq * invD - mean * mean;
  float rs = rsqrtf(var + 1e-5f);
  float r = (v - mean) * rs * g[lane < 56 ? lane : 0] + b[lane < 56 ? lane : 0];
  if (lane < 32) xsb[(size_t)n * 32 + lane] = f2bf(r);
  else if (lane < 56) xvf[(size_t)n * 24 + lane - 32] = r;
}

// ---------- block-1 message: indices/sh/af hoisted above barrier; MFMA P-dot ----------
__global__ __launch_bounds__(256) void k_msg1f(
    const int* __restrict__ esrc, const float* __restrict__ sh, const ushort16* __restrict__ hb,
    const ushort16* __restrict__ Pb, const float* __restrict__ xv,
    const ushort16* __restrict__ Bpw, ushort16* __restrict__ msg) {
  __shared__ ushort16 Wlds[16][392];   // padded: row stride 784B breaks bank alignment
  int w = threadIdx.x >> 6, lane = threadIdx.x & 63;
  int e0 = __builtin_amdgcn_readfirstlane(blockIdx.x * 16);
  int row = lane & 15, q = lane >> 4;
  // hoisted phase-2 loads: latency hides under phase-1 MFMA + barrier
  int sK[4];
  float shK[4][3];
  short8 afK[4];
#pragma unroll
  for (int k = 0; k < 4; ++k) {
    int e = e0 + w * 4 + k;
    sK[k] = __builtin_amdgcn_readfirstlane(esrc[e]);
    shK[k][0] = sh[e * 3 + 0]; shK[k][1] = sh[e * 3 + 1]; shK[k][2] = sh[e * 3 + 2];
    afK[k] = *reinterpret_cast<const short8*>(hb + (size_t)e * 32 + q * 8);
  }
  // ---- phase 1: Wlds = h1b[16 rows] @ Bpw via 24 MFMA ----
  short8 a1 = *reinterpret_cast<const short8*>(hb + (size_t)(e0 + row) * 32 + q * 8);
  floatx4 zero = {0.f, 0.f, 0.f, 0.f};
#pragma unroll
  for (int t6 = 0; t6 < 6; ++t6) {
    int T = w * 6 + t6;
    short8 b1 = *reinterpret_cast<const short8*>(Bpw + (size_t)T * 512 + lane * 8);
    floatx4 acc = __builtin_amdgcn_mfma_f32_16x16x32_bf16(a1, b1, zero, 0, 0, 0);
#pragma unroll
    for (int r = 0; r < 4; ++r)
      Wlds[q * 4 + r][T * 16 + row] = f2bf(acc[r]);
  }
  __syncthreads();   // only barrier: Wlds complete
  // ---- phase 2: 4 edges per wave, lane owns channel; P-dot on MFMA ----
  int lv = lane - 32;
  int vq = (lv >= 0) ? ((lv / 3 > 7) ? 7 : lv / 3) : 0;  // v index for vector channels
  int vi = (lv >= 0) ? (lv - (lv / 3) * 3) : 0;          // component i
  int c2 = 32 + row; if (c2 > 39) c2 = 39;
#pragma unroll
  for (int k = 0; k < 4; ++k) {
    int e = e0 + w * 4 + k;
    int s = sK[k];
    float sh0 = shK[k][0], sh1 = shK[k][1], sh2 = shK[k][2];
    // issue P-row loads first so they overlap the V-path compute
    const ushort16* Pr = Pb + (size_t)s * 1280;
    short8 bf0 = *reinterpret_cast<const short8*>(Pr + row * 32 + q * 8);
    short8 bf1 = *reinterpret_cast<const short8*>(Pr + (16 + row) * 32 + q * 8);
    short8 bf2 = *reinterpret_cast<const short8*>(Pr + c2 * 32 + q * 8);
    const float* xr = xv + (size_t)s * 24;   // wave-uniform -> s_load broadcast
    const ushort16* wp = &Wlds[w * 4 + k][0];
    float vterm, mult;
    if (lane < 32) {
      mult = 1.0f;
      uint4 wv = *reinterpret_cast<const uint4*>(wp + lane * 8);
      float ww[8] = {bflo(wv.x), bfhi(wv.x), bflo(wv.y), bfhi(wv.y),
                     bflo(wv.z), bfhi(wv.z), bflo(wv.w), bfhi(wv.w)};
      // reassociated: a_i = sum_u xv[u][i]*w[u]; vterm = K_DOT*(a . sh)
      float a0 = 0.f, a1s = 0.f, a2 = 0.f;
#pragma unroll
      for (int u = 0; u < 8; ++u) {
        a0 += xr[u * 3 + 0] * ww[u];
        a1s += xr[u * 3 + 1] * ww[u];
        a2 += xr[u * 3 + 2] * ww[u];
      }
      vterm = K_DOT * (a0 * sh0 + a1s * sh1 + a2 * sh2);
    } else {
      float shi = (vi == 0) ? sh0 : (vi == 1) ? sh1 : sh2;
      float s1 = (vi == 0) ? sh1 : (vi == 1) ? sh2 : sh0;   // sh[(vi+1)%3]
      float s2 = (vi == 0) ? sh2 : (vi == 1) ? sh0 : sh1;   // sh[(vi+2)%3]
      mult = shi;
      uint4 wvs = *reinterpret_cast<const uint4*>(wp + 256 + vq * 8);
      uint4 wvv = *reinterpret_cast<const uint4*>(wp + 320 + vq * 8);
      float vsw[8] = {bflo(wvs.x), bfhi(wvs.x), bflo(wvs.y), bfhi(wvs.y),
                      bflo(wvs.z), bfhi(wvs.z), bflo(wvs.w), bfhi(wvs.w)};
      float vvw[8] = {bflo(wvv.x), bfhi(wvv.x), bflo(wvv.y), bfhi(wvv.y),
                      bflo(wvv.z), bfhi(wvv.z), bflo(wvv.w), bfhi(wvv.w)};
      // reassociated: cross term = s2*sum(xi1*vvw) - s1*sum(xi2*vvw)
      float b0 = 0.f, b1 = 0.f, b2 = 0.f;
#pragma unroll
      for (int u = 0; u < 8; ++u) {
        float xu0 = xr[u * 3], xu1 = xr[u * 3 + 1], xu2 = xr[u * 3 + 2];
        float xui = (vi == 0) ? xu0 : (vi == 1) ? xu1 : xu2;
        float xi1 = (vi == 0) ? xu1 : (vi == 1) ? xu2 : xu0;  // xv[(vi+1)%3]
        float xi2 = (vi == 0) ? xu2 : (vi == 1) ? xu0 : xu1;  // xv[(vi+2)%3]
        b0 += xui * vsw[u];
        b1 += xi1 * vvw[u];
        b2 += xi2 * vvw[u];
      }
      vterm = b0 + s2 * b1 - s1 * b2;
    }
    // P path via MFMA: 3 tiles of 16 channels; redistribute in registers
    floatx4 p0 = __builtin_amdgcn_mfma_f32_16x16x32_bf16(afK[k], bf0, zero, 0, 0, 0);
    floatx4 p1 = __builtin_amdgcn_mfma_f32_16x16x32_bf16(afK[k], bf1, zero, 0, 0, 0);
    floatx4 p2 = __builtin_amdgcn_mfma_f32_16x16x32_bf16(afK[k], bf2, zero, 0, 0, 0);
    float pv2 = __shfl(p2[0], vq, 64);
    float pdot = (lane < 16) ? p0[0] : (lane < 32) ? p1[0] : pv2;
    if (lane < 56) msg[(size_t)e * 56 + lane] = f2bf(pdot * mult + vterm);
  }
}

// ---------- block-2 message: indices/sh/af hoisted above barrier; single-MFMA P-dot ----------
__global__ __launch_bounds__(256) void k_msg2f(
    const int* __restrict__ esrc, const float* __restrict__ sh, const ushort16* __restrict__ hb,
    const ushort16* __restrict__ Pb, const float* __restrict__ xv,
    const ushort16* __restrict__ Bpw, ushort16* __restrict__ msg) {
  __shared__ ushort16 Wlds[16][136];   // padded row stride 272B
  int w = threadIdx.x >> 6, lane = threadIdx.x & 63;
  int e0 = __builtin_amdgcn_readfirstlane(blockIdx.x * 16);
  int row = lane & 15, q = lane >> 4;
  // hoisted phase-2 loads
  int sK[4];
  float shK[4][3];
  short8 afK[4];
#pragma unroll
  for (int k = 0; k < 4; ++k) {
    int e = e0 + w * 4 + k;
    sK[k] = __builtin_amdgcn_readfirstlane(esrc[e]);
    shK[k][0] = sh[e * 3 + 0]; shK[k][1] = sh[e * 3 + 1]; shK[k][2] = sh[e * 3 + 2];
    afK[k] = *reinterpret_cast<const short8*>(hb + (size_t)e * 32 + q * 8);
  }
  // ---- phase 1: 8 tiles, 2 per wave ----
  short8 a1 = *reinterpret_cast<const short8*>(hb + (size_t)(e0 + row) * 32 + q * 8);
  floatx4 zero = {0.f, 0.f, 0.f, 0.f};
#pragma unroll
  for (int t2 = 0; t2 < 2; ++t2) {
    int T = w * 2 + t2;
    short8 b1 = *reinterpret_cast<const short8*>(Bpw + (size_t)T * 512 + lane * 8);
    floatx4 acc = __builtin_amdgcn_mfma_f32_16x16x32_bf16(a1, b1, zero, 0, 0, 0);
#pragma unroll
    for (int r = 0; r < 4; ++r)
      Wlds[q * 4 + r][T * 16 + row] = f2bf(acc[r]);
  }
  __syncthreads();
  // ---- phase 2: 4 edges per wave; V path shuffle-free, P via 1 MFMA ----
  int cch = lane & 15;   // this lane's output channel
#pragma unroll
  for (int k = 0; k < 4; ++k) {
    int e = e0 + w * 4 + k;
    int s = sK[k];
    float sh0 = shK[k][0], sh1 = shK[k][1], sh2 = shK[k][2];
    short8 bf = *reinterpret_cast<const short8*>(Pb + (size_t)s * 512 + row * 32 + q * 8);
    const float* xr = xv + (size_t)s * 24;
    // V path: reassociated a_i = sum_u xv[u][i]*w[u]; vterm = K_DOT*(a . sh)
    uint4 wv = *reinterpret_cast<const uint4*>(&Wlds[w * 4 + k][0] + cch * 8);
    float ww[8] = {bflo(wv.x), bfhi(wv.x), bflo(wv.y), bfhi(wv.y),
                   bflo(wv.z), bfhi(wv.z), bflo(wv.w), bfhi(wv.w)};
    float a0 = 0.f, a1s = 0.f, a2 = 0.f;
#pragma unroll
    for (int u = 0; u < 8; ++u) {
      a0 += xr[u * 3 + 0] * ww[u];
      a1s += xr[u * 3 + 1] * ww[u];
      a2 += xr[u * 3 + 2] * ww[u];
    }
    float vterm = K_DOT * (a0 * sh0 + a1s * sh1 + a2 * sh2);
    // P path via one MFMA (16 channels)
    floatx4 p0 = __builtin_amdgcn_mfma_f32_16x16x32_bf16(afK[k], bf, zero, 0, 0, 0);
    if (lane < 16) msg[(size_t)e * 16 + lane] = f2bf(p0[0] + vterm);
  }
}

// ---------- bucket gather + LayerNorm: one wave per node; index prefetch ----------
__global__ __launch_bounds__(256) void k_gather_ln(
    const int* __restrict__ deg, const int* __restrict__ eidx,
    const ushort16* __restrict__ msg, int D,
    const float* __restrict__ g, const float* __restrict__ b,
    ushort16* __restrict__ xsb, float* __restrict__ xvf, float* __restrict__ outf) {
  int n = __builtin_amdgcn_readfirstlane(blockIdx.x * 4 + (threadIdx.x >> 6));
  int lane = threadIdx.x & 63;
  int cnt = deg[n]; if (cnt > 64) cnt = 64;
  const int* ep = eidx + (size_t)n * 64;
  float v = 0.f;
  int e_n = (cnt > 0) ? __builtin_amdgcn_readfirstlane(ep[0]) : 0;
  for (int j = 0; j < cnt; ++j) {
    int e = e_n;
    if (j + 1 < cnt) e_n = __builtin_amdgcn_readfirstlane(ep[j + 1]);
    if (lane < D) v += bfs(msg[(size_t)e * D + lane]);
  }
  v *= K_PRELN;
  if (lane >= D) v = 0.f;
  float sm = v, sq = v * v;
#pragma unroll
  for (int off = 32; off > 0; off >>= 1) {
    sm += __shfl_xor(sm, off, 64);
    sq += __shfl_xor(sq, off, 64);
  }
  float invD = 1.0f / (float)D;
  float mean = sm * invD;
  float var = sq * invD - mean * mean;
  float rs = rsqrtf(var + 1e-5f);
  float r = (v - mean) * rs * g[lane < D ? lane : 0] + b[lane < D ? lane : 0];
  if (outf) {
    if (lane < D) outf[(size_t)n * D + lane] = r;
  } else {
    if (lane < 32) xsb[(size_t)n * 32 + lane] = f2bf(r);
    else if (lane < 56) xvf[(size_t)n * 24 + lane - 32] = r;
  }
}

extern "C" void kernel_launch(void* const* d_in, const int* in_sizes, int n_in,
                              void* d_out, int out_size, void* d_ws, size_t ws_size,
                              hipStream_t stream) {
  const float* pos = (const float*)d_in[0];
  const int* z = (const int*)d_in[1];
  const int* mol = (const int*)d_in[2];
  const int* esrc = (const int*)d_in[3];
  const int* edst = (const int*)d_in[4];
  const float* Ez = (const float*)d_in[5];
  const float* Em = (const float*)d_in[6];
  const float* b0W1 = (const float*)d_in[7];
  const float* b0W2 = (const float*)d_in[8];
  const float* b0g = (const float*)d_in[9];
  const float* b0b = (const float*)d_in[10];
  const float* b1W1 = (const float*)d_in[11];
  const float* b1W2 = (const float*)d_in[12];
  const float* b1g = (const float*)d_in[13];
  const float* b1b = (const float*)d_in[14];
  const float* b2W1 = (const float*)d_in[15];
  const float* b2W2 = (const float*)d_in[16];
  const float* b2g = (const float*)d_in[17];
  const float* b2b = (const float*)d_in[18];
  float* out = (float*)d_out;

  float* ws = (float*)d_ws;
  size_t o = 0;
  int* combo = (int*)(ws + o); o += NNODES;
  int* deg = (int*)(ws + o); o += NNODES;
  int* eidx = (int*)(ws + o); o += (size_t)NNODES * 64;  // fixed-capacity buckets
  ushort16* X0cb = (ushort16*)(ws + o); o += 8192;       // 256x64 bf16
  ushort16* xs1b = (ushort16*)(ws + o); o += 131072;     // 8192x32 bf16
  float* xv1 = ws + o; o += (size_t)NNODES * 24;         // 8192x24 f32
  ushort16* h0b = (ushort16*)(ws + o); o += (size_t)NEDGES * 16;   // 65536x32 bf16
  ushort16* h1b = (ushort16*)(ws + o); o += (size_t)NEDGES * 16;
  ushort16* h2b = (ushort16*)(ws + o); o += (size_t)NEDGES * 16;
  float* shb = ws + o; o += (size_t)NEDGES * 3;
  ushort16* Bp0 = (ushort16*)(ws + o); o += 40960;       // 80x2x512 bf16
  ushort16* Bp1 = (ushort16*)(ws + o); o += 20480;       // 80x512 bf16
  ushort16* Bp2 = (ushort16*)(ws + o); o += 8192;        // 32x512 bf16
  ushort16* Bpw1 = (ushort16*)(ws + o); o += 6144;       // 24x512 bf16
  ushort16* Bpw2 = (ushort16*)(ws + o); o += 2048;       // 8x512 bf16
  ushort16* P12 = (ushort16*)(ws + o); o += (size_t)NNODES * 640;  // 8192x1280 bf16
  ushort16* msgb = (ushort16*)(ws + o); o += (size_t)NEDGES * 28;  // 65536x56 bf16 (7.3 MB)

  ushort16* P0c = P12;          // 256x1280 bf16, consumed (gather0) before gemm1 overwrites
  ushort16* xs2b = xs1b;        // xs1b dead after gemm P12-1
  float* xv2 = xv1;             // xv1 dead after k_msg1f
  ushort16* msg16 = msgb;       // block-1 msg dead after gather1

  hipMemsetAsync(deg, 0, NNODES * sizeof(int), stream);

  k_prep<<<1472, 256, 0, stream>>>(pos, z, mol, esrc, edst, Ez, Em,
                                   b0W1, b1W1, b2W1, b0W2, b1W2, b2W2,
                                   combo, X0cb, shb, h0b, h1b, h2b,
                                   Bp0, Bp1, Bp2, Bpw1, Bpw2, deg, eidx);

  // block 0 (msg fused into gather: inline MFMA P-dot per incoming edge)
  k_gemm_mfma<<<dim3(4, 20), 256, 0, stream>>>(X0cb, Bp0, P0c, 1280, 64);
  k_gather0<<<2048, 256, 0, stream>>>(deg, eidx, combo, esrc, shb, h0b, P0c,
                                      b0g, b0b, xs1b, xv1);

  // block 1 (Wedge computed in-LDS inside k_msg1f)
  k_gemm_mfma<<<dim3(128, 20), 256, 0, stream>>>(xs1b, Bp1, P12, 1280, 32);
  k_msg1f<<<4096, 256, 0, stream>>>(esrc, shb, h1b, P12, xv1, Bpw1, msgb);
  k_gather_ln<<<2048, 256, 0, stream>>>(deg, eidx, msgb, 56, b1g, b1b, xs2b, xv2, nullptr);

  // block 2
  k_gemm_mfma<<<dim3(128, 8), 256, 0, stream>>>(xs2b, Bp2, P12, 512, 32);
  k_msg2f<<<4096, 256, 0, stream>>>(esrc, shb, h2b, P12, xv2, Bpw2, msg16);
  k_gather_ln<<<2048, 256, 0, stream>>>(deg, eidx, msg16, 16, b2g, b2b, nullptr, nullptr, out);
}